// Round 1
// baseline (753.888 us; speedup 1.0000x reference)
//
#include <hip/hip_runtime.h>

#define NDIM 64
#define RS 66  // LDS row stride in floats: (66*r + k) % 32 = (2r+k)%32 -> 2-way alias (free)

// ---------------- BN fold: W1f = W1 * s, b1f = (b1-mean)*s + beta ----------------
__global__ __launch_bounds__(256) void fold_bn_kernel(
    const float* __restrict__ W1, const float* __restrict__ b1,
    const float* __restrict__ gamma, const float* __restrict__ beta,
    const float* __restrict__ mean, const float* __restrict__ var,
    float* __restrict__ W1f, float* __restrict__ b1f, int LD)
{
    int tid = blockIdx.x * blockDim.x + threadIdx.x;
    if (tid >= LD) return;
    float s = gamma[tid] * rsqrtf(var[tid] + 1e-5f);
    b1f[tid] = (b1[tid] - mean[tid]) * s + beta[tid];
    int l = tid >> 6, c = tid & 63;
    const float* wsrc = W1 + (size_t)l * 4096;
    float* wdst = W1f + (size_t)l * 4096;
    for (int k = 0; k < 64; ++k) wdst[k * 64 + c] = wsrc[k * 64 + c] * s;
}

// ---------------- CSR build ----------------
__global__ __launch_bounds__(256) void count_kernel(
    const int* __restrict__ dst, int* __restrict__ cnt, int E)
{
    int tid = blockIdx.x * blockDim.x + threadIdx.x;
    if (tid < E) atomicAdd(&cnt[dst[tid]], 1);
}

__global__ __launch_bounds__(256) void alloc_kernel(
    const int* __restrict__ cnt, int* __restrict__ offs,
    int* __restrict__ cursor, int* __restrict__ gcnt, int N)
{
    __shared__ int sd[256];
    __shared__ int sbase;
    int t = threadIdx.x;
    int i = blockIdx.x * 256 + t;
    int v = (i < N) ? cnt[i] : 0;
    sd[t] = v;
    __syncthreads();
    // Hillis-Steele inclusive scan
    for (int d = 1; d < 256; d <<= 1) {
        int x = sd[t];
        int y = (t >= d) ? sd[t - d] : 0;
        __syncthreads();
        sd[t] = x + y;
        __syncthreads();
    }
    int incl = sd[t];
    if (t == 255) sbase = atomicAdd(gcnt, incl);  // segment base; order irrelevant
    __syncthreads();
    int off = sbase + incl - v;
    if (i < N) { offs[i] = off; cursor[i] = off; }
}

__global__ __launch_bounds__(256) void fill_kernel(
    const int* __restrict__ src, const int* __restrict__ dst,
    int* __restrict__ cursor, int* __restrict__ ssrc, int E)
{
    int tid = blockIdx.x * blockDim.x + threadIdx.x;
    if (tid < E) {
        int d = dst[tid];
        int pos = atomicAdd(&cursor[d], 1);
        ssrc[pos] = src[tid];
    }
}

// ---------------- gather: pre[i] = h[i] + sum_{j in N(i)} h[j] ----------------
// one wave per node, lane = column (coalesced 256B per neighbor row)
__global__ __launch_bounds__(256) void gather_kernel(
    const float* __restrict__ h, const int* __restrict__ offs,
    const int* __restrict__ ends, const int* __restrict__ ssrc,
    float* __restrict__ pre, int N)
{
    int node = blockIdx.x * (blockDim.x >> 6) + (threadIdx.x >> 6);
    int lane = threadIdx.x & 63;
    if (node >= N) return;
    int beg = offs[node], end = ends[node];
    float acc = h[(size_t)node * NDIM + lane];
    for (int e = beg; e < end; ++e) {
        int j = ssrc[e];
        acc += h[(size_t)j * NDIM + lane];
    }
    pre[(size_t)node * NDIM + lane] = acc;
}

// ---------------- fused MLP: h = [relu](relu(BN(pre@W1+b1)) @ W2 + b2); jk += h --------
// one wave per 64-row tile; lane = row; 64 accumulators/lane; W rows wave-uniform.
__global__ __launch_bounds__(64) void mlp_kernel(
    const float* __restrict__ pre, float* __restrict__ hout,
    float* __restrict__ jk,
    const float* __restrict__ W1f, const float* __restrict__ b1f,
    const float* __restrict__ W2, const float* __restrict__ b2,
    int N, int relu_out, int first, int write_h)
{
    __shared__ float lds[64 * RS];
    int lane = threadIdx.x;          // 0..63
    int row0 = blockIdx.x * 64;
    float* myRow = lds + lane * RS;

    // stage 64 pre-rows into LDS, coalesced (float2 per lane, 2 rows/iter)
    int c2 = lane & 31, rr = lane >> 5;
    for (int it = 0; it < 32; ++it) {
        int r = it * 2 + rr;
        int grow = row0 + r;
        float2 v = make_float2(0.f, 0.f);
        if (grow < N) v = *(const float2*)(pre + (size_t)grow * NDIM + c2 * 2);
        *(float2*)(lds + r * RS + c2 * 2) = v;
    }
    __syncthreads();

    float acc[NDIM];
    #pragma unroll
    for (int c = 0; c < NDIM; ++c) acc[c] = 0.f;
    for (int k = 0; k < NDIM; ++k) {
        float p = myRow[k];                      // ds_read, 2-way alias (free)
        const float* Wk = W1f + k * NDIM;        // wave-uniform
        #pragma unroll
        for (int c = 0; c < NDIM; ++c) acc[c] = fmaf(p, Wk[c], acc[c]);
    }
    // bias (BN-folded) + ReLU, park z in own LDS row (per-lane, no barrier needed)
    #pragma unroll
    for (int c = 0; c < NDIM; ++c) acc[c] = fmaxf(acc[c] + b1f[c], 0.f);
    #pragma unroll
    for (int c = 0; c < NDIM / 2; ++c) {
        float2 v = make_float2(acc[2 * c], acc[2 * c + 1]);
        *(float2*)(myRow + 2 * c) = v;
    }

    #pragma unroll
    for (int c = 0; c < NDIM; ++c) acc[c] = 0.f;
    for (int k = 0; k < NDIM; ++k) {
        float p = myRow[k];
        const float* Wk = W2 + k * NDIM;
        #pragma unroll
        for (int c = 0; c < NDIM; ++c) acc[c] = fmaf(p, Wk[c], acc[c]);
    }
    #pragma unroll
    for (int c = 0; c < NDIM; ++c) {
        float hv = acc[c] + b2[c];
        if (relu_out) hv = fmaxf(hv, 0.f);
        acc[c] = hv;
    }
    // park h in own LDS row, then cooperative coalesced writeback
    #pragma unroll
    for (int c = 0; c < NDIM / 2; ++c) {
        float2 v = make_float2(acc[2 * c], acc[2 * c + 1]);
        *(float2*)(myRow + 2 * c) = v;
    }
    __syncthreads();
    for (int it = 0; it < 32; ++it) {
        int r = it * 2 + rr;
        int grow = row0 + r;
        if (grow >= N) continue;
        float2 hv = *(const float2*)(lds + r * RS + c2 * 2);
        if (write_h) *(float2*)(hout + (size_t)grow * NDIM + c2 * 2) = hv;
        float2 jv;
        if (first) jv = hv;
        else {
            float2 o = *(const float2*)(jk + (size_t)grow * NDIM + c2 * 2);
            jv = make_float2(o.x + hv.x, o.y + hv.y);
        }
        *(float2*)(jk + (size_t)grow * NDIM + c2 * 2) = jv;
    }
}

extern "C" void kernel_launch(void* const* d_in, const int* in_sizes, int n_in,
                              void* d_out, int out_size, void* d_ws, size_t ws_size,
                              hipStream_t stream) {
    const float* x     = (const float*)d_in[0];
    const int*   src   = (const int*)  d_in[1];
    const int*   dst   = (const int*)  d_in[2];
    const float* W1    = (const float*)d_in[3];
    const float* b1    = (const float*)d_in[4];
    const float* gamma = (const float*)d_in[5];
    const float* beta  = (const float*)d_in[6];
    const float* mean  = (const float*)d_in[7];
    const float* var   = (const float*)d_in[8];
    const float* W2    = (const float*)d_in[9];
    const float* b2    = (const float*)d_in[10];

    int N = in_sizes[0] / NDIM;
    int E = in_sizes[1];
    int L = in_sizes[3] / (NDIM * NDIM);
    float* out = (float*)d_out;

    char* w = (char*)d_ws;
    size_t off = 0;
    auto carve = [&](size_t bytes) -> void* {
        void* p = w + off;
        off += (bytes + 255) & ~(size_t)255;
        return p;
    };
    float* bufA   = (float*)carve((size_t)N * NDIM * 4);
    float* bufB   = (float*)carve((size_t)N * NDIM * 4);
    int*   ssrc   = (int*)  carve((size_t)E * 4);
    int*   cnt    = (int*)  carve((size_t)N * 4 + 4);   // gcnt appended
    int*   gcnt   = cnt + N;
    int*   offs   = (int*)  carve((size_t)N * 4);
    int*   cursor = (int*)  carve((size_t)N * 4);
    float* W1f    = (float*)carve((size_t)L * NDIM * NDIM * 4);
    float* b1f    = (float*)carve((size_t)L * NDIM * 4);

    hipMemsetAsync(cnt, 0, (size_t)N * 4 + 4, stream);
    fold_bn_kernel<<<(L * NDIM + 255) / 256, 256, 0, stream>>>(
        W1, b1, gamma, beta, mean, var, W1f, b1f, L * NDIM);
    count_kernel<<<(E + 255) / 256, 256, 0, stream>>>(dst, cnt, E);
    alloc_kernel<<<(N + 255) / 256, 256, 0, stream>>>(cnt, offs, cursor, gcnt, N);
    fill_kernel<<<(E + 255) / 256, 256, 0, stream>>>(src, dst, cursor, ssrc, E);

    const float* h = x;
    for (int l = 0; l < L; ++l) {
        gather_kernel<<<(N + 3) / 4, 256, 0, stream>>>(h, offs, cursor, ssrc, bufA, N);
        mlp_kernel<<<(N + 63) / 64, 64, 0, stream>>>(
            bufA, bufB, out,
            W1f + (size_t)l * NDIM * NDIM, b1f + (size_t)l * NDIM,
            W2  + (size_t)l * NDIM * NDIM, b2  + (size_t)l * NDIM,
            N, (l < L - 1) ? 1 : 0, (l == 0) ? 1 : 0, (l < L - 1) ? 1 : 0);
        h = bufB;
    }
}

// Round 2
// 516.778 us; speedup vs baseline: 1.4588x; 1.4588x over previous
//
#include <hip/hip_runtime.h>

#define NDIM 64
#define RS 66  // LDS row stride in floats: 2-way bank alias only (free per m136)

// ---------------- BN fold: W1f = W1 * s, b1f = (b1-mean)*s + beta ----------------
__global__ __launch_bounds__(256) void fold_bn_kernel(
    const float* __restrict__ W1, const float* __restrict__ b1,
    const float* __restrict__ gamma, const float* __restrict__ beta,
    const float* __restrict__ mean, const float* __restrict__ var,
    float* __restrict__ W1f, float* __restrict__ b1f, int LD)
{
    int tid = blockIdx.x * blockDim.x + threadIdx.x;
    if (tid >= LD) return;
    float s = gamma[tid] * rsqrtf(var[tid] + 1e-5f);
    b1f[tid] = (b1[tid] - mean[tid]) * s + beta[tid];
    int l = tid >> 6, c = tid & 63;
    const float* wsrc = W1 + (size_t)l * 4096;
    float* wdst = W1f + (size_t)l * 4096;
    for (int k = 0; k < 64; ++k) wdst[k * 64 + c] = wsrc[k * 64 + c] * s;
}

// ---------------- CSR pass 1: count + per-edge rank (atomic return) ----------------
__global__ __launch_bounds__(256) void count_rank_kernel(
    const int* __restrict__ dst, int* __restrict__ cnt,
    int* __restrict__ rank, int E)
{
    int tid = blockIdx.x * blockDim.x + threadIdx.x;
    if (tid < E) rank[tid] = atomicAdd(&cnt[dst[tid]], 1);
}

// ---------------- CSR pass 2: block scan -> segment bases (order-scrambled OK) -----
__global__ __launch_bounds__(256) void alloc_kernel(
    const int* __restrict__ cnt, int* __restrict__ offs,
    int* __restrict__ ends, int* __restrict__ gcnt, int N)
{
    __shared__ int sd[256];
    __shared__ int sbase;
    int t = threadIdx.x;
    int i = blockIdx.x * 256 + t;
    int v = (i < N) ? cnt[i] : 0;
    sd[t] = v;
    __syncthreads();
    for (int d = 1; d < 256; d <<= 1) {   // Hillis-Steele inclusive scan
        int x = sd[t];
        int y = (t >= d) ? sd[t - d] : 0;
        __syncthreads();
        sd[t] = x + y;
        __syncthreads();
    }
    int incl = sd[t];
    if (t == 255) sbase = atomicAdd(gcnt, incl);
    __syncthreads();
    int off = sbase + incl - v;
    if (i < N) { offs[i] = off; ends[i] = off + v; }
}

// ---------------- CSR pass 3: atomic-free fill ----------------
__global__ __launch_bounds__(256) void fill_kernel(
    const int* __restrict__ src, const int* __restrict__ dst,
    const int* __restrict__ offs, const int* __restrict__ rank,
    int* __restrict__ ssrc, int E)
{
    int tid = blockIdx.x * blockDim.x + threadIdx.x;
    if (tid < E) {
        int d = dst[tid];
        ssrc[offs[d] + rank[tid]] = src[tid];
    }
}

// ---------------- gather: pre[i] = h[i] + sum_{j in N(i)} h[j] ----------------
// one wave per node; 4 lane-groups of 16 process 4 edges/iter with float4 loads
__device__ inline float4 shfl_xor_f4(float4 v, int mask) {
    v.x = __shfl_xor(v.x, mask, 64);
    v.y = __shfl_xor(v.y, mask, 64);
    v.z = __shfl_xor(v.z, mask, 64);
    v.w = __shfl_xor(v.w, mask, 64);
    return v;
}

__global__ __launch_bounds__(256) void gather_kernel(
    const float* __restrict__ h, const int* __restrict__ offs,
    const int* __restrict__ ends, const int* __restrict__ ssrc,
    float* __restrict__ pre, int N)
{
    int node = blockIdx.x * (blockDim.x >> 6) + (threadIdx.x >> 6);
    int lane = threadIdx.x & 63;
    if (node >= N) return;
    int grp = lane >> 4;        // which edge within a 4-edge bundle
    int q   = lane & 15;        // which float4 of the 64-float row
    int beg = offs[node], end = ends[node];

    float4 self = make_float4(0.f, 0.f, 0.f, 0.f);
    if (grp == 0) self = *(const float4*)(h + (size_t)node * NDIM + q * 4);

    float4 acc = make_float4(0.f, 0.f, 0.f, 0.f);
    for (int e = beg; e < end; e += 4) {
        int idx = e + grp;
        if (idx < end) {
            int j = ssrc[idx];
            float4 v = *(const float4*)(h + (size_t)j * NDIM + q * 4);
            acc.x += v.x; acc.y += v.y; acc.z += v.z; acc.w += v.w;
        }
    }
    // reduce across the 4 lane-groups (lane bits 4 and 5)
    float4 o = shfl_xor_f4(acc, 16);
    acc.x += o.x; acc.y += o.y; acc.z += o.z; acc.w += o.w;
    o = shfl_xor_f4(acc, 32);
    acc.x += o.x; acc.y += o.y; acc.z += o.z; acc.w += o.w;

    if (grp == 0) {
        acc.x += self.x; acc.y += self.y; acc.z += self.z; acc.w += self.w;
        *(float4*)(pre + (size_t)node * NDIM + q * 4) = acc;
    }
}

// ---------------- fused MLP: h = [relu](relu(BN(pre@W1+b1)) @ W2 + b2); jk += h ----
__global__ __launch_bounds__(64) void mlp_kernel(
    const float* __restrict__ pre, float* __restrict__ hout,
    float* __restrict__ jk,
    const float* __restrict__ W1f, const float* __restrict__ b1f,
    const float* __restrict__ W2, const float* __restrict__ b2,
    int N, int relu_out, int first, int write_h)
{
    __shared__ float lds[64 * RS];
    int lane = threadIdx.x;
    int row0 = blockIdx.x * 64;
    float* myRow = lds + lane * RS;

    int c2 = lane & 31, rr = lane >> 5;
    for (int it = 0; it < 32; ++it) {
        int r = it * 2 + rr;
        int grow = row0 + r;
        float2 v = make_float2(0.f, 0.f);
        if (grow < N) v = *(const float2*)(pre + (size_t)grow * NDIM + c2 * 2);
        *(float2*)(lds + r * RS + c2 * 2) = v;
    }
    __syncthreads();

    float acc[NDIM];
    #pragma unroll
    for (int c = 0; c < NDIM; ++c) acc[c] = 0.f;
    for (int k = 0; k < NDIM; ++k) {
        float p = myRow[k];
        const float* Wk = W1f + k * NDIM;   // wave-uniform -> s_load
        #pragma unroll
        for (int c = 0; c < NDIM; ++c) acc[c] = fmaf(p, Wk[c], acc[c]);
    }
    #pragma unroll
    for (int c = 0; c < NDIM; ++c) acc[c] = fmaxf(acc[c] + b1f[c], 0.f);
    #pragma unroll
    for (int c = 0; c < NDIM / 2; ++c)
        *(float2*)(myRow + 2 * c) = make_float2(acc[2 * c], acc[2 * c + 1]);

    #pragma unroll
    for (int c = 0; c < NDIM; ++c) acc[c] = 0.f;
    for (int k = 0; k < NDIM; ++k) {
        float p = myRow[k];
        const float* Wk = W2 + k * NDIM;
        #pragma unroll
        for (int c = 0; c < NDIM; ++c) acc[c] = fmaf(p, Wk[c], acc[c]);
    }
    #pragma unroll
    for (int c = 0; c < NDIM; ++c) {
        float hv = acc[c] + b2[c];
        if (relu_out) hv = fmaxf(hv, 0.f);
        acc[c] = hv;
    }
    #pragma unroll
    for (int c = 0; c < NDIM / 2; ++c)
        *(float2*)(myRow + 2 * c) = make_float2(acc[2 * c], acc[2 * c + 1]);
    __syncthreads();
    for (int it = 0; it < 32; ++it) {
        int r = it * 2 + rr;
        int grow = row0 + r;
        if (grow >= N) continue;
        float2 hv = *(const float2*)(lds + r * RS + c2 * 2);
        if (write_h) *(float2*)(hout + (size_t)grow * NDIM + c2 * 2) = hv;
        float2 jv;
        if (first) jv = hv;
        else {
            float2 o = *(const float2*)(jk + (size_t)grow * NDIM + c2 * 2);
            jv = make_float2(o.x + hv.x, o.y + hv.y);
        }
        *(float2*)(jk + (size_t)grow * NDIM + c2 * 2) = jv;
    }
}

extern "C" void kernel_launch(void* const* d_in, const int* in_sizes, int n_in,
                              void* d_out, int out_size, void* d_ws, size_t ws_size,
                              hipStream_t stream) {
    const float* x     = (const float*)d_in[0];
    const int*   src   = (const int*)  d_in[1];
    const int*   dst   = (const int*)  d_in[2];
    const float* W1    = (const float*)d_in[3];
    const float* b1    = (const float*)d_in[4];
    const float* gamma = (const float*)d_in[5];
    const float* beta  = (const float*)d_in[6];
    const float* mean  = (const float*)d_in[7];
    const float* var   = (const float*)d_in[8];
    const float* W2    = (const float*)d_in[9];
    const float* b2    = (const float*)d_in[10];

    int N = in_sizes[0] / NDIM;
    int E = in_sizes[1];
    int L = in_sizes[3] / (NDIM * NDIM);
    float* out = (float*)d_out;

    char* w = (char*)d_ws;
    size_t off = 0;
    auto carve = [&](size_t bytes) -> void* {
        void* p = w + off;
        off += (bytes + 255) & ~(size_t)255;
        return p;
    };
    float* bufA = (float*)carve((size_t)N * NDIM * 4);
    float* bufB = (float*)carve((size_t)N * NDIM * 4);
    int*   ssrc = (int*)  carve((size_t)E * 4);
    int*   cnt  = (int*)  carve((size_t)N * 4 + 4);   // gcnt appended
    int*   gcnt = cnt + N;
    int*   offs = (int*)  carve((size_t)N * 4);
    int*   ends = (int*)  carve((size_t)N * 4);
    float* W1f  = (float*)carve((size_t)L * NDIM * NDIM * 4);
    float* b1f  = (float*)carve((size_t)L * NDIM * 4);
    int*   rank = (int*)bufB;   // alias: rank consumed in fill, before mlp writes bufB

    hipMemsetAsync(cnt, 0, (size_t)N * 4 + 4, stream);
    fold_bn_kernel<<<(L * NDIM + 255) / 256, 256, 0, stream>>>(
        W1, b1, gamma, beta, mean, var, W1f, b1f, L * NDIM);
    count_rank_kernel<<<(E + 255) / 256, 256, 0, stream>>>(dst, cnt, rank, E);
    alloc_kernel<<<(N + 255) / 256, 256, 0, stream>>>(cnt, offs, ends, gcnt, N);
    fill_kernel<<<(E + 255) / 256, 256, 0, stream>>>(src, dst, offs, rank, ssrc, E);

    const float* h = x;
    for (int l = 0; l < L; ++l) {
        gather_kernel<<<(N + 3) / 4, 256, 0, stream>>>(h, offs, ends, ssrc, bufA, N);
        mlp_kernel<<<(N + 63) / 64, 64, 0, stream>>>(
            bufA, bufB, out,
            W1f + (size_t)l * NDIM * NDIM, b1f + (size_t)l * NDIM,
            W2  + (size_t)l * NDIM * NDIM, b2  + (size_t)l * NDIM,
            N, (l < L - 1) ? 1 : 0, (l == 0) ? 1 : 0, (l < L - 1) ? 1 : 0);
        h = bufB;
    }
}

// Round 3
// 425.104 us; speedup vs baseline: 1.7734x; 1.2156x over previous
//
#include <hip/hip_runtime.h>

#define NDIM 64
#define RS2 65  // LDS row stride: bank = (r+k)%32 -> 2 lanes/bank for wave64 = free (m136)

// ---------------- BN fold: W1f = W1 * s, b1f = (b1-mean)*s + beta ----------------
__global__ __launch_bounds__(256) void fold_bn_kernel(
    const float* __restrict__ W1, const float* __restrict__ b1,
    const float* __restrict__ gamma, const float* __restrict__ beta,
    const float* __restrict__ mean, const float* __restrict__ var,
    float* __restrict__ W1f, float* __restrict__ b1f, int LD)
{
    int tid = blockIdx.x * blockDim.x + threadIdx.x;
    if (tid >= LD) return;
    float s = gamma[tid] * rsqrtf(var[tid] + 1e-5f);
    b1f[tid] = (b1[tid] - mean[tid]) * s + beta[tid];
    int l = tid >> 6, c = tid & 63;
    const float* wsrc = W1 + (size_t)l * 4096;
    float* wdst = W1f + (size_t)l * 4096;
    for (int k = 0; k < 64; ++k) wdst[k * 64 + c] = wsrc[k * 64 + c] * s;
}

// ---------------- CSR pass 1: count + per-edge rank (atomic return) ----------------
__global__ __launch_bounds__(256) void count_rank_kernel(
    const int* __restrict__ dst, int* __restrict__ cnt,
    int* __restrict__ rank, int E)
{
    int tid = blockIdx.x * blockDim.x + threadIdx.x;
    if (tid < E) rank[tid] = atomicAdd(&cnt[dst[tid]], 1);
}

// ---------------- CSR pass 2: block scan -> segment bases (order-scrambled OK) -----
__global__ __launch_bounds__(256) void alloc_kernel(
    const int* __restrict__ cnt, int* __restrict__ offs,
    int* __restrict__ ends, int* __restrict__ gcnt, int N)
{
    __shared__ int sd[256];
    __shared__ int sbase;
    int t = threadIdx.x;
    int i = blockIdx.x * 256 + t;
    int v = (i < N) ? cnt[i] : 0;
    sd[t] = v;
    __syncthreads();
    for (int d = 1; d < 256; d <<= 1) {   // Hillis-Steele inclusive scan
        int x = sd[t];
        int y = (t >= d) ? sd[t - d] : 0;
        __syncthreads();
        sd[t] = x + y;
        __syncthreads();
    }
    int incl = sd[t];
    if (t == 255) sbase = atomicAdd(gcnt, incl);
    __syncthreads();
    int off = sbase + incl - v;
    if (i < N) { offs[i] = off; ends[i] = off + v; }
}

// ---------------- CSR pass 3: atomic-free fill ----------------
__global__ __launch_bounds__(256) void fill_kernel(
    const int* __restrict__ src, const int* __restrict__ dst,
    const int* __restrict__ offs, const int* __restrict__ rank,
    int* __restrict__ ssrc, int E)
{
    int tid = blockIdx.x * blockDim.x + threadIdx.x;
    if (tid < E) {
        int d = dst[tid];
        ssrc[offs[d] + rank[tid]] = src[tid];
    }
}

// ---------------- gather: pre[i] = h[i] + sum_{j in N(i)} h[j] ----------------
// one wave per node; 4 lane-groups of 16, float4 loads, unroll x2 (8 edges in flight)
__device__ inline float4 shfl_xor_f4(float4 v, int mask) {
    v.x = __shfl_xor(v.x, mask, 64);
    v.y = __shfl_xor(v.y, mask, 64);
    v.z = __shfl_xor(v.z, mask, 64);
    v.w = __shfl_xor(v.w, mask, 64);
    return v;
}

__global__ __launch_bounds__(256) void gather_kernel(
    const float* __restrict__ h, const int* __restrict__ offs,
    const int* __restrict__ ends, const int* __restrict__ ssrc,
    float* __restrict__ pre, int N)
{
    int node = blockIdx.x * (blockDim.x >> 6) + (threadIdx.x >> 6);
    int lane = threadIdx.x & 63;
    if (node >= N) return;
    int grp = lane >> 4;        // edge slot within a 4-edge bundle
    int q   = lane & 15;        // which float4 of the 64-float row
    int beg = offs[node], end = ends[node];

    float4 self = make_float4(0.f, 0.f, 0.f, 0.f);
    if (grp == 0) self = *(const float4*)(h + (size_t)node * NDIM + q * 4);

    float4 acc1 = make_float4(0.f, 0.f, 0.f, 0.f);
    float4 acc2 = make_float4(0.f, 0.f, 0.f, 0.f);
    for (int e = beg; e < end; e += 8) {
        int i1 = e + grp, i2 = e + grp + 4;
        int j1 = (i1 < end) ? ssrc[i1] : -1;
        int j2 = (i2 < end) ? ssrc[i2] : -1;
        if (j1 >= 0) {
            float4 v = *(const float4*)(h + (size_t)j1 * NDIM + q * 4);
            acc1.x += v.x; acc1.y += v.y; acc1.z += v.z; acc1.w += v.w;
        }
        if (j2 >= 0) {
            float4 v = *(const float4*)(h + (size_t)j2 * NDIM + q * 4);
            acc2.x += v.x; acc2.y += v.y; acc2.z += v.z; acc2.w += v.w;
        }
    }
    acc1.x += acc2.x; acc1.y += acc2.y; acc1.z += acc2.z; acc1.w += acc2.w;
    float4 o = shfl_xor_f4(acc1, 16);
    acc1.x += o.x; acc1.y += o.y; acc1.z += o.z; acc1.w += o.w;
    o = shfl_xor_f4(acc1, 32);
    acc1.x += o.x; acc1.y += o.y; acc1.z += o.z; acc1.w += o.w;

    if (grp == 0) {
        acc1.x += self.x; acc1.y += self.y; acc1.z += self.z; acc1.w += self.w;
        *(float4*)(pre + (size_t)node * NDIM + q * 4) = acc1;
    }
}

// ---------------- fused MLP, column-split: 4 waves per 64-row tile ----------------
// lane = row, wave w computes cols [16w,16w+16) of both GEMMs; z round-trips via LDS.
__global__ __launch_bounds__(256, 6) void mlp_kernel(
    const float* __restrict__ pre, float* __restrict__ hout,
    float* __restrict__ jk,
    const float* __restrict__ W1f, const float* __restrict__ b1f,
    const float* __restrict__ W2, const float* __restrict__ b2,
    int N, int relu_out, int first, int write_h)
{
    __shared__ float lds[64 * RS2];   // 16.6 KB
    int t = threadIdx.x;
    int lane = t & 63;
    int c0 = __builtin_amdgcn_readfirstlane((t >> 6) * 16);  // wave-uniform -> SGPR
    int row0 = blockIdx.x * 64;

    // stage 64x64 tile, float4 coalesced reads, scalar LDS writes (stride 65)
    #pragma unroll
    for (int it = 0; it < 4; ++it) {
        int f4 = it * 256 + t;          // 0..1023
        int r = f4 >> 4, c4 = f4 & 15;
        int grow = row0 + r;
        float4 v = make_float4(0.f, 0.f, 0.f, 0.f);
        if (grow < N) v = *(const float4*)(pre + (size_t)grow * NDIM + c4 * 4);
        float* p = lds + r * RS2 + c4 * 4;
        p[0] = v.x; p[1] = v.y; p[2] = v.z; p[3] = v.w;
    }
    __syncthreads();

    const float* myRow = lds + lane * RS2;
    float acc[16];
    #pragma unroll
    for (int c = 0; c < 16; ++c) acc[c] = 0.f;
    #pragma unroll 4
    for (int k = 0; k < NDIM; ++k) {
        float p = myRow[k];                       // ds_read, 2-way alias (free)
        const float* Wk = W1f + k * NDIM + c0;    // uniform -> s_load_dwordx
        #pragma unroll
        for (int c = 0; c < 16; ++c) acc[c] = fmaf(p, Wk[c], acc[c]);
    }
    __syncthreads();                              // all waves done reading pre
    #pragma unroll
    for (int c = 0; c < 16; ++c)
        lds[lane * RS2 + c0 + c] = fmaxf(acc[c] + b1f[c0 + c], 0.f);
    __syncthreads();

    #pragma unroll
    for (int c = 0; c < 16; ++c) acc[c] = 0.f;
    #pragma unroll 4
    for (int k = 0; k < NDIM; ++k) {
        float p = myRow[k];
        const float* Wk = W2 + k * NDIM + c0;
        #pragma unroll
        for (int c = 0; c < 16; ++c) acc[c] = fmaf(p, Wk[c], acc[c]);
    }
    __syncthreads();                              // all waves done reading z
    #pragma unroll
    for (int c = 0; c < 16; ++c) {
        float hv = acc[c] + b2[c0 + c];
        if (relu_out) hv = fmaxf(hv, 0.f);
        lds[lane * RS2 + c0 + c] = hv;
    }
    __syncthreads();

    // cooperative coalesced writeback (float4)
    #pragma unroll
    for (int it = 0; it < 4; ++it) {
        int f4 = it * 256 + t;
        int r = f4 >> 4, c4 = f4 & 15;
        int grow = row0 + r;
        if (grow >= N) continue;
        const float* p = lds + r * RS2 + c4 * 4;
        float4 hv = make_float4(p[0], p[1], p[2], p[3]);
        if (write_h) *(float4*)(hout + (size_t)grow * NDIM + c4 * 4) = hv;
        float4 jv;
        if (first) jv = hv;
        else {
            float4 o = *(const float4*)(jk + (size_t)grow * NDIM + c4 * 4);
            jv = make_float4(o.x + hv.x, o.y + hv.y, o.z + hv.z, o.w + hv.w);
        }
        *(float4*)(jk + (size_t)grow * NDIM + c4 * 4) = jv;
    }
}

extern "C" void kernel_launch(void* const* d_in, const int* in_sizes, int n_in,
                              void* d_out, int out_size, void* d_ws, size_t ws_size,
                              hipStream_t stream) {
    const float* x     = (const float*)d_in[0];
    const int*   src   = (const int*)  d_in[1];
    const int*   dst   = (const int*)  d_in[2];
    const float* W1    = (const float*)d_in[3];
    const float* b1    = (const float*)d_in[4];
    const float* gamma = (const float*)d_in[5];
    const float* beta  = (const float*)d_in[6];
    const float* mean  = (const float*)d_in[7];
    const float* var   = (const float*)d_in[8];
    const float* W2    = (const float*)d_in[9];
    const float* b2    = (const float*)d_in[10];

    int N = in_sizes[0] / NDIM;
    int E = in_sizes[1];
    int L = in_sizes[3] / (NDIM * NDIM);
    float* out = (float*)d_out;

    char* w = (char*)d_ws;
    size_t off = 0;
    auto carve = [&](size_t bytes) -> void* {
        void* p = w + off;
        off += (bytes + 255) & ~(size_t)255;
        return p;
    };
    float* bufA = (float*)carve((size_t)N * NDIM * 4);
    float* bufB = (float*)carve((size_t)N * NDIM * 4);
    int*   ssrc = (int*)  carve((size_t)E * 4);
    int*   cnt  = (int*)  carve((size_t)N * 4 + 4);   // gcnt appended
    int*   gcnt = cnt + N;
    int*   offs = (int*)  carve((size_t)N * 4);
    int*   ends = (int*)  carve((size_t)N * 4);
    float* W1f  = (float*)carve((size_t)L * NDIM * NDIM * 4);
    float* b1f  = (float*)carve((size_t)L * NDIM * 4);
    int*   rank = (int*)bufB;   // alias: rank consumed in fill, before mlp writes bufB

    hipMemsetAsync(cnt, 0, (size_t)N * 4 + 4, stream);
    fold_bn_kernel<<<(L * NDIM + 255) / 256, 256, 0, stream>>>(
        W1, b1, gamma, beta, mean, var, W1f, b1f, L * NDIM);
    count_rank_kernel<<<(E + 255) / 256, 256, 0, stream>>>(dst, cnt, rank, E);
    alloc_kernel<<<(N + 255) / 256, 256, 0, stream>>>(cnt, offs, ends, gcnt, N);
    fill_kernel<<<(E + 255) / 256, 256, 0, stream>>>(src, dst, offs, rank, ssrc, E);

    const float* h = x;
    for (int l = 0; l < L; ++l) {
        gather_kernel<<<(N + 3) / 4, 256, 0, stream>>>(h, offs, ends, ssrc, bufA, N);
        mlp_kernel<<<(N + 63) / 64, 256, 0, stream>>>(
            bufA, bufB, out,
            W1f + (size_t)l * NDIM * NDIM, b1f + (size_t)l * NDIM,
            W2  + (size_t)l * NDIM * NDIM, b2  + (size_t)l * NDIM,
            N, (l < L - 1) ? 1 : 0, (l == 0) ? 1 : 0, (l < L - 1) ? 1 : 0);
        h = bufB;
    }
}

// Round 4
// 402.124 us; speedup vs baseline: 1.8748x; 1.0571x over previous
//
#include <hip/hip_runtime.h>
#include <hip/hip_fp16.h>

#define NDIM 64
#define RS2 65  // LDS row stride: bank = (r+k)%32 -> 2 lanes/bank for wave64 = free (m136)

// ---------------- BN fold: W1f = W1 * s, b1f = (b1-mean)*s + beta ----------------
__global__ __launch_bounds__(256) void fold_bn_kernel(
    const float* __restrict__ W1, const float* __restrict__ b1,
    const float* __restrict__ gamma, const float* __restrict__ beta,
    const float* __restrict__ mean, const float* __restrict__ var,
    float* __restrict__ W1f, float* __restrict__ b1f, int LD)
{
    int tid = blockIdx.x * blockDim.x + threadIdx.x;
    if (tid >= LD) return;
    float s = gamma[tid] * rsqrtf(var[tid] + 1e-5f);
    b1f[tid] = (b1[tid] - mean[tid]) * s + beta[tid];
    int l = tid >> 6, c = tid & 63;
    const float* wsrc = W1 + (size_t)l * 4096;
    float* wdst = W1f + (size_t)l * 4096;
    for (int k = 0; k < 64; ++k) wdst[k * 64 + c] = wsrc[k * 64 + c] * s;
}

// ---------------- x (fp32) -> fp16 rows for the gather ----------------
__global__ __launch_bounds__(256) void to_half_kernel(
    const float* __restrict__ x, __half* __restrict__ x16, int n4)
{
    int tid = blockIdx.x * blockDim.x + threadIdx.x;
    if (tid >= n4) return;
    float4 v = *(const float4*)(x + (size_t)tid * 4);
    __half2* dp = (__half2*)(x16 + (size_t)tid * 4);
    dp[0] = __floats2half2_rn(v.x, v.y);
    dp[1] = __floats2half2_rn(v.z, v.w);
}

// ---------------- CSR pass 1: count + per-edge rank (atomic return) ----------------
__global__ __launch_bounds__(256) void count_rank_kernel(
    const int* __restrict__ dst, int* __restrict__ cnt,
    int* __restrict__ rank, int E)
{
    int tid = blockIdx.x * blockDim.x + threadIdx.x;
    if (tid < E) rank[tid] = atomicAdd(&cnt[dst[tid]], 1);
}

// ---------------- CSR pass 2: block scan -> segment bases (order-scrambled OK) -----
__global__ __launch_bounds__(256) void alloc_kernel(
    const int* __restrict__ cnt, int* __restrict__ offs,
    int* __restrict__ ends, int* __restrict__ gcnt, int N)
{
    __shared__ int sd[256];
    __shared__ int sbase;
    int t = threadIdx.x;
    int i = blockIdx.x * 256 + t;
    int v = (i < N) ? cnt[i] : 0;
    sd[t] = v;
    __syncthreads();
    for (int d = 1; d < 256; d <<= 1) {   // Hillis-Steele inclusive scan
        int x = sd[t];
        int y = (t >= d) ? sd[t - d] : 0;
        __syncthreads();
        sd[t] = x + y;
        __syncthreads();
    }
    int incl = sd[t];
    if (t == 255) sbase = atomicAdd(gcnt, incl);
    __syncthreads();
    int off = sbase + incl - v;
    if (i < N) { offs[i] = off; ends[i] = off + v; }
}

// ---------------- CSR pass 3: atomic-free fill ----------------
__global__ __launch_bounds__(256) void fill_kernel(
    const int* __restrict__ src, const int* __restrict__ dst,
    const int* __restrict__ offs, const int* __restrict__ rank,
    int* __restrict__ ssrc, int E)
{
    int tid = blockIdx.x * blockDim.x + threadIdx.x;
    if (tid < E) {
        int d = dst[tid];
        ssrc[offs[d] + rank[tid]] = src[tid];
    }
}

// ---------------- gather: pre[i] = h[i] + sum_{j in N(i)} h[j], h in fp16 ----------
// one wave per node; 4 lane-groups of 16, 8B fp16x4 loads, unroll x2 (8 edges in flight)
__device__ inline float4 shfl_xor_f4(float4 v, int mask) {
    v.x = __shfl_xor(v.x, mask, 64);
    v.y = __shfl_xor(v.y, mask, 64);
    v.z = __shfl_xor(v.z, mask, 64);
    v.w = __shfl_xor(v.w, mask, 64);
    return v;
}

__device__ inline float4 load_h4(const __half* __restrict__ h, size_t row, int q) {
    const __half2* p = (const __half2*)(h + row * NDIM + q * 4);
    __half2 a = p[0], b = p[1];      // adjacent 4B loads -> merged dwordx2
    float2 fa = __half22float2(a), fb = __half22float2(b);
    return make_float4(fa.x, fa.y, fb.x, fb.y);
}

__global__ __launch_bounds__(256) void gather_kernel(
    const __half* __restrict__ h, const int* __restrict__ offs,
    const int* __restrict__ ends, const int* __restrict__ ssrc,
    float* __restrict__ pre, int N)
{
    int node = blockIdx.x * (blockDim.x >> 6) + (threadIdx.x >> 6);
    int lane = threadIdx.x & 63;
    if (node >= N) return;
    int grp = lane >> 4;        // edge slot within a 4-edge bundle
    int q   = lane & 15;        // which fp16x4 chunk of the 64-elem row
    int beg = offs[node], end = ends[node];

    float4 self = make_float4(0.f, 0.f, 0.f, 0.f);
    if (grp == 0) self = load_h4(h, (size_t)node, q);

    float4 acc1 = make_float4(0.f, 0.f, 0.f, 0.f);
    float4 acc2 = make_float4(0.f, 0.f, 0.f, 0.f);
    for (int e = beg; e < end; e += 8) {
        int i1 = e + grp, i2 = e + grp + 4;
        int j1 = (i1 < end) ? ssrc[i1] : -1;
        int j2 = (i2 < end) ? ssrc[i2] : -1;
        if (j1 >= 0) {
            float4 v = load_h4(h, (size_t)j1, q);
            acc1.x += v.x; acc1.y += v.y; acc1.z += v.z; acc1.w += v.w;
        }
        if (j2 >= 0) {
            float4 v = load_h4(h, (size_t)j2, q);
            acc2.x += v.x; acc2.y += v.y; acc2.z += v.z; acc2.w += v.w;
        }
    }
    acc1.x += acc2.x; acc1.y += acc2.y; acc1.z += acc2.z; acc1.w += acc2.w;
    float4 o = shfl_xor_f4(acc1, 16);
    acc1.x += o.x; acc1.y += o.y; acc1.z += o.z; acc1.w += o.w;
    o = shfl_xor_f4(acc1, 32);
    acc1.x += o.x; acc1.y += o.y; acc1.z += o.z; acc1.w += o.w;

    if (grp == 0) {
        acc1.x += self.x; acc1.y += self.y; acc1.z += self.z; acc1.w += self.w;
        *(float4*)(pre + (size_t)node * NDIM + q * 4) = acc1;
    }
}

// ---------------- fused MLP, column-split: 4 waves per 64-row tile ----------------
// lane = row, wave w computes cols [16w,16w+16); z via LDS; h written back as fp16.
__global__ __launch_bounds__(256, 6) void mlp_kernel(
    const float* __restrict__ pre, __half* __restrict__ h16out,
    float* __restrict__ jk,
    const float* __restrict__ W1f, const float* __restrict__ b1f,
    const float* __restrict__ W2, const float* __restrict__ b2,
    int N, int relu_out, int first, int write_h)
{
    __shared__ float lds[64 * RS2];   // 16.6 KB
    int t = threadIdx.x;
    int lane = t & 63;
    int c0 = __builtin_amdgcn_readfirstlane((t >> 6) * 16);  // wave-uniform -> SGPR
    int row0 = blockIdx.x * 64;

    #pragma unroll
    for (int it = 0; it < 4; ++it) {
        int f4 = it * 256 + t;          // 0..1023
        int r = f4 >> 4, c4 = f4 & 15;
        int grow = row0 + r;
        float4 v = make_float4(0.f, 0.f, 0.f, 0.f);
        if (grow < N) v = *(const float4*)(pre + (size_t)grow * NDIM + c4 * 4);
        float* p = lds + r * RS2 + c4 * 4;
        p[0] = v.x; p[1] = v.y; p[2] = v.z; p[3] = v.w;
    }
    __syncthreads();

    const float* myRow = lds + lane * RS2;
    float acc[16];
    #pragma unroll
    for (int c = 0; c < 16; ++c) acc[c] = 0.f;
    #pragma unroll 4
    for (int k = 0; k < NDIM; ++k) {
        float p = myRow[k];                       // ds_read, 2-way alias (free)
        const float* Wk = W1f + k * NDIM + c0;    // uniform -> s_load_dwordx
        #pragma unroll
        for (int c = 0; c < 16; ++c) acc[c] = fmaf(p, Wk[c], acc[c]);
    }
    __syncthreads();                              // all waves done reading pre
    #pragma unroll
    for (int c = 0; c < 16; ++c)
        lds[lane * RS2 + c0 + c] = fmaxf(acc[c] + b1f[c0 + c], 0.f);
    __syncthreads();

    #pragma unroll
    for (int c = 0; c < 16; ++c) acc[c] = 0.f;
    #pragma unroll 4
    for (int k = 0; k < NDIM; ++k) {
        float p = myRow[k];
        const float* Wk = W2 + k * NDIM + c0;
        #pragma unroll
        for (int c = 0; c < 16; ++c) acc[c] = fmaf(p, Wk[c], acc[c]);
    }
    __syncthreads();                              // all waves done reading z
    #pragma unroll
    for (int c = 0; c < 16; ++c) {
        float hv = acc[c] + b2[c0 + c];
        if (relu_out) hv = fmaxf(hv, 0.f);
        lds[lane * RS2 + c0 + c] = hv;
    }
    __syncthreads();

    // cooperative coalesced writeback: jk (fp32) + next-layer h (fp16)
    #pragma unroll
    for (int it = 0; it < 4; ++it) {
        int f4 = it * 256 + t;
        int r = f4 >> 4, c4 = f4 & 15;
        int grow = row0 + r;
        if (grow >= N) continue;
        const float* p = lds + r * RS2 + c4 * 4;
        float4 hv = make_float4(p[0], p[1], p[2], p[3]);
        if (write_h) {
            __half2* dp = (__half2*)(h16out + (size_t)grow * NDIM + c4 * 4);
            dp[0] = __floats2half2_rn(hv.x, hv.y);
            dp[1] = __floats2half2_rn(hv.z, hv.w);
        }
        float4 jv;
        if (first) jv = hv;
        else {
            float4 o = *(const float4*)(jk + (size_t)grow * NDIM + c4 * 4);
            jv = make_float4(o.x + hv.x, o.y + hv.y, o.z + hv.z, o.w + hv.w);
        }
        *(float4*)(jk + (size_t)grow * NDIM + c4 * 4) = jv;
    }
}

extern "C" void kernel_launch(void* const* d_in, const int* in_sizes, int n_in,
                              void* d_out, int out_size, void* d_ws, size_t ws_size,
                              hipStream_t stream) {
    const float* x     = (const float*)d_in[0];
    const int*   src   = (const int*)  d_in[1];
    const int*   dst   = (const int*)  d_in[2];
    const float* W1    = (const float*)d_in[3];
    const float* b1    = (const float*)d_in[4];
    const float* gamma = (const float*)d_in[5];
    const float* beta  = (const float*)d_in[6];
    const float* mean  = (const float*)d_in[7];
    const float* var   = (const float*)d_in[8];
    const float* W2    = (const float*)d_in[9];
    const float* b2    = (const float*)d_in[10];

    int N = in_sizes[0] / NDIM;
    int E = in_sizes[1];
    int L = in_sizes[3] / (NDIM * NDIM);
    float* out = (float*)d_out;

    char* w = (char*)d_ws;
    size_t off = 0;
    auto carve = [&](size_t bytes) -> void* {
        void* p = w + off;
        off += (bytes + 255) & ~(size_t)255;
        return p;
    };
    float*  bufA = (float*) carve((size_t)N * NDIM * 4);   // pre
    __half* h16  = (__half*)carve((size_t)N * NDIM * 2);   // fp16 h (and x16 for layer 0)
    int*    ssrc = (int*)   carve((size_t)E * 4);
    int*    cnt  = (int*)   carve((size_t)N * 4 + 4);      // gcnt appended
    int*    gcnt = cnt + N;
    int*    offs = (int*)   carve((size_t)N * 4);
    int*    ends = (int*)   carve((size_t)N * 4);
    int*    rank = (int*)   carve((size_t)E * 4);
    float*  W1f  = (float*) carve((size_t)L * NDIM * NDIM * 4);
    float*  b1f  = (float*) carve((size_t)L * NDIM * 4);

    hipMemsetAsync(cnt, 0, (size_t)N * 4 + 4, stream);
    fold_bn_kernel<<<(L * NDIM + 255) / 256, 256, 0, stream>>>(
        W1, b1, gamma, beta, mean, var, W1f, b1f, L * NDIM);
    to_half_kernel<<<(N * NDIM / 4 + 255) / 256, 256, 0, stream>>>(x, h16, N * NDIM / 4);
    count_rank_kernel<<<(E + 255) / 256, 256, 0, stream>>>(dst, cnt, rank, E);
    alloc_kernel<<<(N + 255) / 256, 256, 0, stream>>>(cnt, offs, ends, gcnt, N);
    fill_kernel<<<(E + 255) / 256, 256, 0, stream>>>(src, dst, offs, rank, ssrc, E);

    for (int l = 0; l < L; ++l) {
        gather_kernel<<<(N + 3) / 4, 256, 0, stream>>>(h16, offs, ends, ssrc, bufA, N);
        // mlp overwrites h16 with next layer's h — safe: this layer's gather already consumed it
        mlp_kernel<<<(N + 63) / 64, 256, 0, stream>>>(
            bufA, h16, out,
            W1f + (size_t)l * NDIM * NDIM, b1f + (size_t)l * NDIM,
            W2  + (size_t)l * NDIM * NDIM, b2  + (size_t)l * NDIM,
            N, (l < L - 1) ? 1 : 0, (l == 0) ? 1 : 0, (l < L - 1) ? 1 : 0);
    }
}

// Round 5
// 370.588 us; speedup vs baseline: 2.0343x; 1.0851x over previous
//
#include <hip/hip_runtime.h>
#include <hip/hip_fp16.h>

#define NDIM 64
#define RS2 65     // LDS row stride: 2-way bank alias only (free per m136)
#define MAXNB 512  // supports N <= 131072 (bucket = dst>>8); this problem: N=100000 -> 391

// ---------------- BN fold: W1f = W1 * s, b1f = (b1-mean)*s + beta ----------------
__global__ __launch_bounds__(256) void fold_bn_kernel(
    const float* __restrict__ W1, const float* __restrict__ b1,
    const float* __restrict__ gamma, const float* __restrict__ beta,
    const float* __restrict__ mean, const float* __restrict__ var,
    float* __restrict__ W1f, float* __restrict__ b1f, int LD)
{
    int tid = blockIdx.x * blockDim.x + threadIdx.x;
    if (tid >= LD) return;
    float s = gamma[tid] * rsqrtf(var[tid] + 1e-5f);
    b1f[tid] = (b1[tid] - mean[tid]) * s + beta[tid];
    int l = tid >> 6, c = tid & 63;
    const float* wsrc = W1 + (size_t)l * 4096;
    float* wdst = W1f + (size_t)l * 4096;
    for (int k = 0; k < 64; ++k) wdst[k * 64 + c] = wsrc[k * 64 + c] * s;
}

// ---------------- x (fp32) -> fp16 rows for the gather ----------------
__global__ __launch_bounds__(256) void to_half_kernel(
    const float* __restrict__ x, __half* __restrict__ x16, int n4)
{
    int tid = blockIdx.x * blockDim.x + threadIdx.x;
    if (tid >= n4) return;
    float4 v = *(const float4*)(x + (size_t)tid * 4);
    __half2* dp = (__half2*)(x16 + (size_t)tid * 4);
    dp[0] = __floats2half2_rn(v.x, v.y);
    dp[1] = __floats2half2_rn(v.z, v.w);
}

// ---------------- CSR build, two-level LDS counting sort ----------------
// Pass A: per-block LDS bucket histogram -> small global atomic merge
__global__ __launch_bounds__(256) void bucket_count_kernel(
    const int* __restrict__ dst, int* __restrict__ bcnt, int E, int NBb)
{
    __shared__ int hist[MAXNB];
    for (int i = threadIdx.x; i < NBb; i += 256) hist[i] = 0;
    __syncthreads();
    int start = blockIdx.x * blockDim.x + threadIdx.x;
    int stride = gridDim.x * blockDim.x;
    for (int e = start; e < E; e += stride)
        atomicAdd(&hist[dst[e] >> 8], 1);          // LDS atomic: on-CU
    __syncthreads();
    for (int i = threadIdx.x; i < NBb; i += 256) {
        int v = hist[i];
        if (v) atomicAdd(&bcnt[i], v);             // ~NBb global atomics/block
    }
}

// Pass B: exclusive scan of bucket counts (NBb <= 512), single block
__global__ __launch_bounds__(512) void bucket_scan_kernel(
    const int* __restrict__ bcnt, int* __restrict__ bbase,
    int* __restrict__ bcursor, int NBb)
{
    __shared__ int sd[512];
    int t = threadIdx.x;
    int v = (t < NBb) ? bcnt[t] : 0;
    sd[t] = v;
    __syncthreads();
    for (int d = 1; d < 512; d <<= 1) {
        int x = sd[t];
        int y = (t >= d) ? sd[t - d] : 0;
        __syncthreads();
        sd[t] = x + y;
        __syncthreads();
    }
    int excl = sd[t] - v;
    if (t < NBb) { bbase[t] = excl; bcursor[t] = excl; }
    if (t == NBb - 1) bbase[NBb] = sd[t];          // total = E
}

// Pass C: scatter edges into bucket-grouped packed array (src | local_dst<<24)
__global__ __launch_bounds__(256) void bucket_scatter_kernel(
    const int* __restrict__ src, const int* __restrict__ dst,
    int* __restrict__ bcursor, unsigned int* __restrict__ packed, int E, int NBb)
{
    __shared__ int hist[MAXNB];
    __shared__ int sbase[MAXNB];
    for (int i = threadIdx.x; i < NBb; i += 256) hist[i] = 0;
    __syncthreads();
    int start = blockIdx.x * blockDim.x + threadIdx.x;
    int stride = gridDim.x * blockDim.x;
    for (int e = start; e < E; e += stride)
        atomicAdd(&hist[dst[e] >> 8], 1);
    __syncthreads();
    for (int i = threadIdx.x; i < NBb; i += 256) {
        int v = hist[i];
        sbase[i] = v ? atomicAdd(&bcursor[i], v) : 0;
    }
    __syncthreads();
    for (int i = threadIdx.x; i < NBb; i += 256) hist[i] = 0;  // reuse as cursor
    __syncthreads();
    for (int e = start; e < E; e += stride) {
        int d = dst[e];
        int b = d >> 8;
        int r = atomicAdd(&hist[b], 1);            // LDS rank
        packed[sbase[b] + r] = (unsigned)src[e] | ((unsigned)(d & 255) << 24);
    }
}

// Pass D: per-bucket counting sort -> ssrc + offs/ends (one block per bucket)
__global__ __launch_bounds__(256) void bucket_csr_kernel(
    const unsigned int* __restrict__ packed, const int* __restrict__ bbase,
    int* __restrict__ ssrc, int* __restrict__ offs, int* __restrict__ ends, int N)
{
    __shared__ int hist[256], scan[256], cur[256];
    int b = blockIdx.x;
    int base = bbase[b], cnt = bbase[b + 1] - base;
    int t = threadIdx.x;
    hist[t] = 0;
    __syncthreads();
    for (int i = t; i < cnt; i += 256)
        atomicAdd(&hist[packed[base + i] >> 24], 1);
    __syncthreads();
    int v = hist[t];
    scan[t] = v;
    __syncthreads();
    for (int d = 1; d < 256; d <<= 1) {
        int x = scan[t];
        int y = (t >= d) ? scan[t - d] : 0;
        __syncthreads();
        scan[t] = x + y;
        __syncthreads();
    }
    int e0 = base + scan[t] - v;                   // exclusive position
    cur[t] = e0;
    int node = b * 256 + t;
    if (node < N) { offs[node] = e0; ends[node] = e0 + v; }
    __syncthreads();
    for (int i = t; i < cnt; i += 256) {
        unsigned p = packed[base + i];
        int pos = atomicAdd(&cur[p >> 24], 1);     // LDS cursor
        ssrc[pos] = (int)(p & 0xFFFFFF);
    }
}

// ---------------- gather: pre[i] = h[i] + sum_{j in N(i)} h[j], h in fp16 ----------
__device__ inline float4 shfl_xor_f4(float4 v, int mask) {
    v.x = __shfl_xor(v.x, mask, 64);
    v.y = __shfl_xor(v.y, mask, 64);
    v.z = __shfl_xor(v.z, mask, 64);
    v.w = __shfl_xor(v.w, mask, 64);
    return v;
}

__device__ inline float4 load_h4(const __half* __restrict__ h, size_t row, int q) {
    const __half2* p = (const __half2*)(h + row * NDIM + q * 4);
    __half2 a = p[0], b = p[1];
    float2 fa = __half22float2(a), fb = __half22float2(b);
    return make_float4(fa.x, fa.y, fb.x, fb.y);
}

__global__ __launch_bounds__(256) void gather_kernel(
    const __half* __restrict__ h, const int* __restrict__ offs,
    const int* __restrict__ ends, const int* __restrict__ ssrc,
    float* __restrict__ pre, int N)
{
    int node = blockIdx.x * (blockDim.x >> 6) + (threadIdx.x >> 6);
    int lane = threadIdx.x & 63;
    if (node >= N) return;
    int grp = lane >> 4;
    int q   = lane & 15;
    int beg = offs[node], end = ends[node];

    float4 self = make_float4(0.f, 0.f, 0.f, 0.f);
    if (grp == 0) self = load_h4(h, (size_t)node, q);

    float4 acc1 = make_float4(0.f, 0.f, 0.f, 0.f);
    float4 acc2 = make_float4(0.f, 0.f, 0.f, 0.f);
    for (int e = beg; e < end; e += 8) {
        int i1 = e + grp, i2 = e + grp + 4;
        int j1 = (i1 < end) ? ssrc[i1] : -1;
        int j2 = (i2 < end) ? ssrc[i2] : -1;
        if (j1 >= 0) {
            float4 v = load_h4(h, (size_t)j1, q);
            acc1.x += v.x; acc1.y += v.y; acc1.z += v.z; acc1.w += v.w;
        }
        if (j2 >= 0) {
            float4 v = load_h4(h, (size_t)j2, q);
            acc2.x += v.x; acc2.y += v.y; acc2.z += v.z; acc2.w += v.w;
        }
    }
    acc1.x += acc2.x; acc1.y += acc2.y; acc1.z += acc2.z; acc1.w += acc2.w;
    float4 o = shfl_xor_f4(acc1, 16);
    acc1.x += o.x; acc1.y += o.y; acc1.z += o.z; acc1.w += o.w;
    o = shfl_xor_f4(acc1, 32);
    acc1.x += o.x; acc1.y += o.y; acc1.z += o.z; acc1.w += o.w;

    if (grp == 0) {
        acc1.x += self.x; acc1.y += self.y; acc1.z += self.z; acc1.w += self.w;
        *(float4*)(pre + (size_t)node * NDIM + q * 4) = acc1;
    }
}

// ---------------- fused MLP, column-split: 4 waves per 64-row tile ----------------
__global__ __launch_bounds__(256, 6) void mlp_kernel(
    const float* __restrict__ pre, __half* __restrict__ h16out,
    float* __restrict__ jk,
    const float* __restrict__ W1f, const float* __restrict__ b1f,
    const float* __restrict__ W2, const float* __restrict__ b2,
    int N, int relu_out, int first, int write_h)
{
    __shared__ float lds[64 * RS2];   // 16.6 KB
    int t = threadIdx.x;
    int lane = t & 63;
    int c0 = __builtin_amdgcn_readfirstlane((t >> 6) * 16);
    int row0 = blockIdx.x * 64;

    #pragma unroll
    for (int it = 0; it < 4; ++it) {
        int f4 = it * 256 + t;
        int r = f4 >> 4, c4 = f4 & 15;
        int grow = row0 + r;
        float4 v = make_float4(0.f, 0.f, 0.f, 0.f);
        if (grow < N) v = *(const float4*)(pre + (size_t)grow * NDIM + c4 * 4);
        float* p = lds + r * RS2 + c4 * 4;
        p[0] = v.x; p[1] = v.y; p[2] = v.z; p[3] = v.w;
    }
    __syncthreads();

    const float* myRow = lds + lane * RS2;
    float acc[16];
    #pragma unroll
    for (int c = 0; c < 16; ++c) acc[c] = 0.f;
    #pragma unroll 4
    for (int k = 0; k < NDIM; ++k) {
        float p = myRow[k];
        const float* Wk = W1f + k * NDIM + c0;
        #pragma unroll
        for (int c = 0; c < 16; ++c) acc[c] = fmaf(p, Wk[c], acc[c]);
    }
    __syncthreads();
    #pragma unroll
    for (int c = 0; c < 16; ++c)
        lds[lane * RS2 + c0 + c] = fmaxf(acc[c] + b1f[c0 + c], 0.f);
    __syncthreads();

    #pragma unroll
    for (int c = 0; c < 16; ++c) acc[c] = 0.f;
    #pragma unroll 4
    for (int k = 0; k < NDIM; ++k) {
        float p = myRow[k];
        const float* Wk = W2 + k * NDIM + c0;
        #pragma unroll
        for (int c = 0; c < 16; ++c) acc[c] = fmaf(p, Wk[c], acc[c]);
    }
    __syncthreads();
    #pragma unroll
    for (int c = 0; c < 16; ++c) {
        float hv = acc[c] + b2[c0 + c];
        if (relu_out) hv = fmaxf(hv, 0.f);
        lds[lane * RS2 + c0 + c] = hv;
    }
    __syncthreads();

    #pragma unroll
    for (int it = 0; it < 4; ++it) {
        int f4 = it * 256 + t;
        int r = f4 >> 4, c4 = f4 & 15;
        int grow = row0 + r;
        if (grow >= N) continue;
        const float* p = lds + r * RS2 + c4 * 4;
        float4 hv = make_float4(p[0], p[1], p[2], p[3]);
        if (write_h) {
            __half2* dp = (__half2*)(h16out + (size_t)grow * NDIM + c4 * 4);
            dp[0] = __floats2half2_rn(hv.x, hv.y);
            dp[1] = __floats2half2_rn(hv.z, hv.w);
        }
        float4 jv;
        if (first) jv = hv;
        else {
            float4 o = *(const float4*)(jk + (size_t)grow * NDIM + c4 * 4);
            jv = make_float4(o.x + hv.x, o.y + hv.y, o.z + hv.z, o.w + hv.w);
        }
        *(float4*)(jk + (size_t)grow * NDIM + c4 * 4) = jv;
    }
}

extern "C" void kernel_launch(void* const* d_in, const int* in_sizes, int n_in,
                              void* d_out, int out_size, void* d_ws, size_t ws_size,
                              hipStream_t stream) {
    const float* x     = (const float*)d_in[0];
    const int*   src   = (const int*)  d_in[1];
    const int*   dst   = (const int*)  d_in[2];
    const float* W1    = (const float*)d_in[3];
    const float* b1    = (const float*)d_in[4];
    const float* gamma = (const float*)d_in[5];
    const float* beta  = (const float*)d_in[6];
    const float* mean  = (const float*)d_in[7];
    const float* var   = (const float*)d_in[8];
    const float* W2    = (const float*)d_in[9];
    const float* b2    = (const float*)d_in[10];

    int N = in_sizes[0] / NDIM;
    int E = in_sizes[1];
    int L = in_sizes[3] / (NDIM * NDIM);
    int NBb = (N + 255) >> 8;            // buckets of 256 nodes
    float* out = (float*)d_out;

    char* w = (char*)d_ws;
    size_t off = 0;
    auto carve = [&](size_t bytes) -> void* {
        void* p = w + off;
        off += (bytes + 255) & ~(size_t)255;
        return p;
    };
    float*  bufA    = (float*) carve((size_t)N * NDIM * 4);   // pre
    __half* h16     = (__half*)carve((size_t)N * NDIM * 2);   // fp16 h
    int*    ssrc    = (int*)   carve((size_t)E * 4);
    unsigned int* packed = (unsigned int*)carve((size_t)E * 4);
    int*    offs    = (int*)   carve((size_t)N * 4);
    int*    ends    = (int*)   carve((size_t)N * 4);
    int*    bcnt    = (int*)   carve((size_t)(MAXNB + 1) * 4);
    int*    bbase   = (int*)   carve((size_t)(MAXNB + 1) * 4);
    int*    bcursor = (int*)   carve((size_t)MAXNB * 4);
    float*  W1f     = (float*) carve((size_t)L * NDIM * NDIM * 4);
    float*  b1f     = (float*) carve((size_t)L * NDIM * 4);

    hipMemsetAsync(bcnt, 0, (size_t)(MAXNB + 1) * 4, stream);
    fold_bn_kernel<<<(L * NDIM + 255) / 256, 256, 0, stream>>>(
        W1, b1, gamma, beta, mean, var, W1f, b1f, L * NDIM);
    to_half_kernel<<<(N * NDIM / 4 + 255) / 256, 256, 0, stream>>>(x, h16, N * NDIM / 4);
    bucket_count_kernel<<<256, 256, 0, stream>>>(dst, bcnt, E, NBb);
    bucket_scan_kernel<<<1, 512, 0, stream>>>(bcnt, bbase, bcursor, NBb);
    bucket_scatter_kernel<<<256, 256, 0, stream>>>(src, dst, bcursor, packed, E, NBb);
    bucket_csr_kernel<<<NBb, 256, 0, stream>>>(packed, bbase, ssrc, offs, ends, N);

    for (int l = 0; l < L; ++l) {
        gather_kernel<<<(N + 3) / 4, 256, 0, stream>>>(h16, offs, ends, ssrc, bufA, N);
        mlp_kernel<<<(N + 63) / 64, 256, 0, stream>>>(
            bufA, h16, out,
            W1f + (size_t)l * NDIM * NDIM, b1f + (size_t)l * NDIM,
            W2  + (size_t)l * NDIM * NDIM, b2  + (size_t)l * NDIM,
            N, (l < L - 1) ? 1 : 0, (l == 0) ? 1 : 0, (l < L - 1) ? 1 : 0);
    }
}

// Round 6
// 338.254 us; speedup vs baseline: 2.2288x; 1.0956x over previous
//
#include <hip/hip_runtime.h>
#include <hip/hip_fp16.h>

#define NDIM 64
#define RS2 65     // LDS row stride: 2-way bank alias only (free per m136)
#define MAXNB 512  // supports N <= 131072 (bucket = dst>>8); this problem: N=100000 -> 391

// ---------------- BN fold: W1f = W1 * s, b1f = (b1-mean)*s + beta ----------------
__global__ __launch_bounds__(256) void fold_bn_kernel(
    const float* __restrict__ W1, const float* __restrict__ b1,
    const float* __restrict__ gamma, const float* __restrict__ beta,
    const float* __restrict__ mean, const float* __restrict__ var,
    float* __restrict__ W1f, float* __restrict__ b1f, int LD)
{
    int tid = blockIdx.x * blockDim.x + threadIdx.x;
    if (tid >= LD) return;
    float s = gamma[tid] * rsqrtf(var[tid] + 1e-5f);
    b1f[tid] = (b1[tid] - mean[tid]) * s + beta[tid];
    int l = tid >> 6, c = tid & 63;
    const float* wsrc = W1 + (size_t)l * 4096;
    float* wdst = W1f + (size_t)l * 4096;
    for (int k = 0; k < 64; ++k) wdst[k * 64 + c] = wsrc[k * 64 + c] * s;
}

// ---------------- x (fp32) -> fp16 rows for the gather ----------------
__global__ __launch_bounds__(256) void to_half_kernel(
    const float* __restrict__ x, __half* __restrict__ x16, int n4)
{
    int tid = blockIdx.x * blockDim.x + threadIdx.x;
    if (tid >= n4) return;
    float4 v = *(const float4*)(x + (size_t)tid * 4);
    __half2* dp = (__half2*)(x16 + (size_t)tid * 4);
    dp[0] = __floats2half2_rn(v.x, v.y);
    dp[1] = __floats2half2_rn(v.z, v.w);
}

// ---------------- CSR build, two-level LDS counting sort ----------------
__global__ __launch_bounds__(256) void bucket_count_kernel(
    const int* __restrict__ dst, int* __restrict__ bcnt, int E, int NBb)
{
    __shared__ int hist[MAXNB];
    for (int i = threadIdx.x; i < NBb; i += 256) hist[i] = 0;
    __syncthreads();
    int start = blockIdx.x * blockDim.x + threadIdx.x;
    int stride = gridDim.x * blockDim.x;
    for (int e = start; e < E; e += stride)
        atomicAdd(&hist[dst[e] >> 8], 1);          // LDS atomic: on-CU
    __syncthreads();
    for (int i = threadIdx.x; i < NBb; i += 256) {
        int v = hist[i];
        if (v) atomicAdd(&bcnt[i], v);
    }
}

__global__ __launch_bounds__(512) void bucket_scan_kernel(
    const int* __restrict__ bcnt, int* __restrict__ bbase,
    int* __restrict__ bcursor, int NBb)
{
    __shared__ int sd[512];
    int t = threadIdx.x;
    int v = (t < NBb) ? bcnt[t] : 0;
    sd[t] = v;
    __syncthreads();
    for (int d = 1; d < 512; d <<= 1) {
        int x = sd[t];
        int y = (t >= d) ? sd[t - d] : 0;
        __syncthreads();
        sd[t] = x + y;
        __syncthreads();
    }
    int excl = sd[t] - v;
    if (t < NBb) { bbase[t] = excl; bcursor[t] = excl; }
    if (t == NBb - 1) bbase[NBb] = sd[t];
}

__global__ __launch_bounds__(256) void bucket_scatter_kernel(
    const int* __restrict__ src, const int* __restrict__ dst,
    int* __restrict__ bcursor, unsigned int* __restrict__ packed, int E, int NBb)
{
    __shared__ int hist[MAXNB];
    __shared__ int sbase[MAXNB];
    for (int i = threadIdx.x; i < NBb; i += 256) hist[i] = 0;
    __syncthreads();
    int start = blockIdx.x * blockDim.x + threadIdx.x;
    int stride = gridDim.x * blockDim.x;
    for (int e = start; e < E; e += stride)
        atomicAdd(&hist[dst[e] >> 8], 1);
    __syncthreads();
    for (int i = threadIdx.x; i < NBb; i += 256) {
        int v = hist[i];
        sbase[i] = v ? atomicAdd(&bcursor[i], v) : 0;
    }
    __syncthreads();
    for (int i = threadIdx.x; i < NBb; i += 256) hist[i] = 0;  // reuse as cursor
    __syncthreads();
    for (int e = start; e < E; e += stride) {
        int d = dst[e];
        int b = d >> 8;
        int r = atomicAdd(&hist[b], 1);            // LDS rank
        packed[sbase[b] + r] = (unsigned)src[e] | ((unsigned)(d & 255) << 24);
    }
}

__global__ __launch_bounds__(256) void bucket_csr_kernel(
    const unsigned int* __restrict__ packed, const int* __restrict__ bbase,
    int* __restrict__ ssrc, int* __restrict__ offs, int* __restrict__ ends, int N)
{
    __shared__ int hist[256], scan[256], cur[256];
    int b = blockIdx.x;
    int base = bbase[b], cnt = bbase[b + 1] - base;
    int t = threadIdx.x;
    hist[t] = 0;
    __syncthreads();
    for (int i = t; i < cnt; i += 256)
        atomicAdd(&hist[packed[base + i] >> 24], 1);
    __syncthreads();
    int v = hist[t];
    scan[t] = v;
    __syncthreads();
    for (int d = 1; d < 256; d <<= 1) {
        int x = scan[t];
        int y = (t >= d) ? scan[t - d] : 0;
        __syncthreads();
        scan[t] = x + y;
        __syncthreads();
    }
    int e0 = base + scan[t] - v;
    cur[t] = e0;
    int node = b * 256 + t;
    if (node < N) { offs[node] = e0; ends[node] = e0 + v; }
    __syncthreads();
    for (int i = t; i < cnt; i += 256) {
        unsigned p = packed[base + i];
        int pos = atomicAdd(&cur[p >> 24], 1);
        ssrc[pos] = (int)(p & 0xFFFFFF);
    }
}

// ---------------- fused GIN layer: gather -> LDS tile -> MLP -> jk/hout ------------
__device__ inline float4 shfl_xor_f4(float4 v, int mask) {
    v.x = __shfl_xor(v.x, mask, 64);
    v.y = __shfl_xor(v.y, mask, 64);
    v.z = __shfl_xor(v.z, mask, 64);
    v.w = __shfl_xor(v.w, mask, 64);
    return v;
}

__device__ inline float4 load_h4(const __half* __restrict__ h, size_t row, int q) {
    const __half2* p = (const __half2*)(h + row * NDIM + q * 4);
    __half2 a = p[0], b = p[1];
    float2 fa = __half22float2(a), fb = __half22float2(b);
    return make_float4(fa.x, fa.y, fb.x, fb.y);
}

__global__ __launch_bounds__(256, 6) void gin_layer_kernel(
    const __half* __restrict__ hin, __half* __restrict__ hout,
    float* __restrict__ jk,
    const int* __restrict__ offs, const int* __restrict__ ends,
    const int* __restrict__ ssrc,
    const float* __restrict__ W1f, const float* __restrict__ b1f,
    const float* __restrict__ W2, const float* __restrict__ b2,
    int N, int relu_out, int first, int write_h)
{
    __shared__ float lds[64 * RS2];   // 16.6 KB: pre tile, then z, then h
    __shared__ int sOffs[64], sEnds[64];
    int t = threadIdx.x;
    int lane = t & 63;
    int w = t >> 6;
    int row0 = blockIdx.x * 64;

    if (t < 64) {
        int node = row0 + t;
        sOffs[t] = (node < N) ? offs[node] : 0;
        sEnds[t] = (node < N) ? ends[node] : 0;
    }
    __syncthreads();

    // ---- gather phase: wave w produces rows w*16 .. w*16+15 of the pre tile ----
    int grp = lane >> 4;   // edge slot within a 4-edge bundle
    int q   = lane & 15;   // fp16x4 chunk of the row
    for (int i = 0; i < 16; ++i) {
        int rl = w * 16 + i;
        int node = row0 + rl;
        if (node >= N) break;
        int beg = sOffs[rl], end = sEnds[rl];

        float4 self = make_float4(0.f, 0.f, 0.f, 0.f);
        if (grp == 0) self = load_h4(hin, (size_t)node, q);

        float4 acc1 = make_float4(0.f, 0.f, 0.f, 0.f);
        float4 acc2 = make_float4(0.f, 0.f, 0.f, 0.f);
        for (int e = beg; e < end; e += 8) {
            int i1 = e + grp, i2 = e + grp + 4;
            int j1 = (i1 < end) ? ssrc[i1] : -1;
            int j2 = (i2 < end) ? ssrc[i2] : -1;
            if (j1 >= 0) {
                float4 v = load_h4(hin, (size_t)j1, q);
                acc1.x += v.x; acc1.y += v.y; acc1.z += v.z; acc1.w += v.w;
            }
            if (j2 >= 0) {
                float4 v = load_h4(hin, (size_t)j2, q);
                acc2.x += v.x; acc2.y += v.y; acc2.z += v.z; acc2.w += v.w;
            }
        }
        acc1.x += acc2.x; acc1.y += acc2.y; acc1.z += acc2.z; acc1.w += acc2.w;
        float4 o = shfl_xor_f4(acc1, 16);
        acc1.x += o.x; acc1.y += o.y; acc1.z += o.z; acc1.w += o.w;
        o = shfl_xor_f4(acc1, 32);
        acc1.x += o.x; acc1.y += o.y; acc1.z += o.z; acc1.w += o.w;

        if (grp == 0) {
            acc1.x += self.x; acc1.y += self.y; acc1.z += self.z; acc1.w += self.w;
            float* p = lds + rl * RS2 + q * 4;
            p[0] = acc1.x; p[1] = acc1.y; p[2] = acc1.z; p[3] = acc1.w;
        }
    }
    __syncthreads();

    // ---- MLP phase: column-split, wave w covers cols [16w, 16w+16) ----
    int c0 = __builtin_amdgcn_readfirstlane(w * 16);
    const float* myRow = lds + lane * RS2;
    float acc[16];
    #pragma unroll
    for (int c = 0; c < 16; ++c) acc[c] = 0.f;
    #pragma unroll 4
    for (int k = 0; k < NDIM; ++k) {
        float p = myRow[k];
        const float* Wk = W1f + k * NDIM + c0;    // wave-uniform -> s_load
        #pragma unroll
        for (int c = 0; c < 16; ++c) acc[c] = fmaf(p, Wk[c], acc[c]);
    }
    __syncthreads();
    #pragma unroll
    for (int c = 0; c < 16; ++c)
        lds[lane * RS2 + c0 + c] = fmaxf(acc[c] + b1f[c0 + c], 0.f);
    __syncthreads();

    #pragma unroll
    for (int c = 0; c < 16; ++c) acc[c] = 0.f;
    #pragma unroll 4
    for (int k = 0; k < NDIM; ++k) {
        float p = myRow[k];
        const float* Wk = W2 + k * NDIM + c0;
        #pragma unroll
        for (int c = 0; c < 16; ++c) acc[c] = fmaf(p, Wk[c], acc[c]);
    }
    __syncthreads();
    #pragma unroll
    for (int c = 0; c < 16; ++c) {
        float hv = acc[c] + b2[c0 + c];
        if (relu_out) hv = fmaxf(hv, 0.f);
        lds[lane * RS2 + c0 + c] = hv;
    }
    __syncthreads();

    // ---- writeback: jk (fp32) + next-layer h (fp16, ping-pong buffer) ----
    #pragma unroll
    for (int it = 0; it < 4; ++it) {
        int f4 = it * 256 + t;
        int r = f4 >> 4, c4 = f4 & 15;
        int grow = row0 + r;
        if (grow >= N) continue;
        const float* p = lds + r * RS2 + c4 * 4;
        float4 hv = make_float4(p[0], p[1], p[2], p[3]);
        if (write_h) {
            __half2* dp = (__half2*)(hout + (size_t)grow * NDIM + c4 * 4);
            dp[0] = __floats2half2_rn(hv.x, hv.y);
            dp[1] = __floats2half2_rn(hv.z, hv.w);
        }
        float4 jv;
        if (first) jv = hv;
        else {
            float4 o = *(const float4*)(jk + (size_t)grow * NDIM + c4 * 4);
            jv = make_float4(o.x + hv.x, o.y + hv.y, o.z + hv.z, o.w + hv.w);
        }
        *(float4*)(jk + (size_t)grow * NDIM + c4 * 4) = jv;
    }
}

extern "C" void kernel_launch(void* const* d_in, const int* in_sizes, int n_in,
                              void* d_out, int out_size, void* d_ws, size_t ws_size,
                              hipStream_t stream) {
    const float* x     = (const float*)d_in[0];
    const int*   src   = (const int*)  d_in[1];
    const int*   dst   = (const int*)  d_in[2];
    const float* W1    = (const float*)d_in[3];
    const float* b1    = (const float*)d_in[4];
    const float* gamma = (const float*)d_in[5];
    const float* beta  = (const float*)d_in[6];
    const float* mean  = (const float*)d_in[7];
    const float* var   = (const float*)d_in[8];
    const float* W2    = (const float*)d_in[9];
    const float* b2    = (const float*)d_in[10];

    int N = in_sizes[0] / NDIM;
    int E = in_sizes[1];
    int L = in_sizes[3] / (NDIM * NDIM);
    int NBb = (N + 255) >> 8;            // buckets of 256 nodes
    float* out = (float*)d_out;

    char* w = (char*)d_ws;
    size_t off = 0;
    auto carve = [&](size_t bytes) -> void* {
        void* p = w + off;
        off += (bytes + 255) & ~(size_t)255;
        return p;
    };
    __half* h16A    = (__half*)carve((size_t)N * NDIM * 2);   // ping
    __half* h16B    = (__half*)carve((size_t)N * NDIM * 2);   // pong
    int*    ssrc    = (int*)   carve((size_t)E * 4);
    unsigned int* packed = (unsigned int*)carve((size_t)E * 4);
    int*    offs    = (int*)   carve((size_t)N * 4);
    int*    ends    = (int*)   carve((size_t)N * 4);
    int*    bcnt    = (int*)   carve((size_t)(MAXNB + 1) * 4);
    int*    bbase   = (int*)   carve((size_t)(MAXNB + 1) * 4);
    int*    bcursor = (int*)   carve((size_t)MAXNB * 4);
    float*  W1f     = (float*) carve((size_t)L * NDIM * NDIM * 4);
    float*  b1f     = (float*) carve((size_t)L * NDIM * 4);

    hipMemsetAsync(bcnt, 0, (size_t)(MAXNB + 1) * 4, stream);
    fold_bn_kernel<<<(L * NDIM + 255) / 256, 256, 0, stream>>>(
        W1, b1, gamma, beta, mean, var, W1f, b1f, L * NDIM);
    to_half_kernel<<<(N * NDIM / 4 + 255) / 256, 256, 0, stream>>>(x, h16A, N * NDIM / 4);
    bucket_count_kernel<<<256, 256, 0, stream>>>(dst, bcnt, E, NBb);
    bucket_scan_kernel<<<1, 512, 0, stream>>>(bcnt, bbase, bcursor, NBb);
    bucket_scatter_kernel<<<256, 256, 0, stream>>>(src, dst, bcursor, packed, E, NBb);
    bucket_csr_kernel<<<NBb, 256, 0, stream>>>(packed, bbase, ssrc, offs, ends, N);

    const __half* hin = h16A;
    __half* hout = h16B;
    for (int l = 0; l < L; ++l) {
        gin_layer_kernel<<<(N + 63) / 64, 256, 0, stream>>>(
            hin, hout, out, offs, ends, ssrc,
            W1f + (size_t)l * NDIM * NDIM, b1f + (size_t)l * NDIM,
            W2  + (size_t)l * NDIM * NDIM, b2  + (size_t)l * NDIM,
            N, (l < L - 1) ? 1 : 0, (l == 0) ? 1 : 0, (l < L - 1) ? 1 : 0);
        const __half* tmp = hin;
        hin = hout;
        hout = (__half*)tmp;
    }
}